// Round 1
// baseline (179.446 us; speedup 1.0000x reference)
//
#include <hip/hip_runtime.h>
#include <hip/hip_bf16.h>
#include <stdint.h>

typedef __attribute__((ext_vector_type(8))) short bf16x8;
typedef __attribute__((ext_vector_type(4))) float f32x4;
typedef __attribute__((ext_vector_type(4))) unsigned int u32x4;

#define NB 16
#define NC 128
#define NH 128
#define NW 128
#define NCO 64
#define HP 130
#define WP 130

// ---------------- prep: per-out-channel scale factor sf[o] = mean|w| ----------------
__global__ void k_sf(const float* __restrict__ cw, float* __restrict__ sf) {
    int o = blockIdx.x;          // 64 blocks
    int t = threadIdx.x;         // 64 threads
    const float* p = cw + o * 1152;
    float s = 0.f;
    for (int i = t; i < 1152; i += 64) s += fabsf(p[i]);
#pragma unroll
    for (int off = 32; off > 0; off >>= 1) s += __shfl_down(s, off);
    if (t == 0) sf[o] = s * (1.0f / 1152.0f);
}

// ---------------- prep: weight sign bits in MFMA B-fragment order ----------------
// flat f = ((p*4+kb)*4+ni)*512 + l*8 + j  ->  sign(w[o][c][kh][kw]) as bf16 bits
// o = ni*16 + (l&15), c = kb*32 + (l>>4)*8 + j, p = kh*3+kw
__global__ void k_wfrag(const float* __restrict__ cw, unsigned short* __restrict__ wf) {
    int f = blockIdx.x * 256 + threadIdx.x;   // < 73728
    int j  = f & 7;
    int l  = (f >> 3) & 63;
    int ni = (f >> 9) & 3;
    int kb = (f >> 11) & 3;
    int p  = f >> 13;
    int o = ni * 16 + (l & 15);
    int c = kb * 32 + (l >> 4) * 8 + j;
    float wv = cw[o * 1152 + c * 9 + p];
    wf[f] = wv > 0.f ? (unsigned short)0x3F80
                     : (wv < 0.f ? (unsigned short)0xBF80 : (unsigned short)0);
}

__device__ __forceinline__ unsigned int sgn_act(float v, float b1v, float av, float b2v) {
    float t = v + b1v;
    t = fmaxf(t, 0.f) + av * fminf(t, 0.f);
    t += b2v;
    return t > 0.f ? 0x3F80u : (t < 0.f ? 0xBF80u : 0u);
}

// ---------------- k1: activation signs -> SB (padded NHWC bf16), shortcut -> out ----------------
// SB[b][hp][wp][c], hp = h+1, wp = w+1; pad rows/cols zeroed (conv zero-padding).
__global__ __launch_bounds__(256) void k1_signs_shortcut(
    const float* __restrict__ x, const float* __restrict__ b1,
    const float* __restrict__ pa, const float* __restrict__ b2,
    const float* __restrict__ pw, unsigned short* __restrict__ SB,
    float* __restrict__ out) {
    __shared__ unsigned int T[128][65];   // [w][o] ; u32 packs signs of c=2o (lo), 2o+1 (hi)
    int bx = blockIdx.x;                  // 16*130
    int nb = bx / 130;
    int hp = bx % 130;
    unsigned short* sbrow = SB + ((size_t)nb * HP + hp) * WP * NC;
    int t = threadIdx.x;
    if (hp == 0 || hp == HP - 1) {        // zero pad rows
        u32x4 z = {0u, 0u, 0u, 0u};
        for (int i = t; i < WP * NC / 8; i += 256)
            ((u32x4*)sbrow)[i] = z;
        return;
    }
    int h = hp - 1;
    int wp2 = t & 63;                     // w pair index: w = 2*wp2, 2*wp2+1
    int oq = t >> 6;                      // 0..3
    const float* xb = x + ((size_t)nb * NC) * NH * NW + (size_t)h * NW + 2 * wp2;
    int s1 = h & 1, h2 = h >> 1;
    float* ob = out + (((size_t)nb * 256 + s1 * 2) * 64 + h2) * 64 + wp2;
#pragma unroll 4
    for (int i = 0; i < 16; ++i) {
        int o = oq * 16 + i;
        int c0 = 2 * o, c1 = c0 + 1;
        float2 x0 = *(const float2*)(xb + (size_t)c0 * NH * NW);
        float2 x1 = *(const float2*)(xb + (size_t)c1 * NH * NW);
        float b10 = b1[c0], b11 = b1[c1];
        float pa0 = pa[c0], pa1 = pa[c1];
        float b20 = b2[c0], b21 = b2[c1];
        unsigned int lo0 = sgn_act(x0.x, b10, pa0, b20);
        unsigned int hi0 = sgn_act(x1.x, b11, pa1, b21);
        unsigned int lo1 = sgn_act(x0.y, b10, pa0, b20);
        unsigned int hi1 = sgn_act(x1.y, b11, pa1, b21);
        T[2 * wp2][o]     = lo0 | (hi0 << 16);
        T[2 * wp2 + 1][o] = lo1 | (hi1 << 16);
        float w0v = pw[c0], w1v = pw[c1];
        ob[(size_t)o * 16384]        = w0v * x0.x + w1v * x1.x;   // s2=0
        ob[(size_t)o * 16384 + 4096] = w0v * x0.y + w1v * x1.y;   // s2=1
    }
    __syncthreads();
    if (t < 32) {                         // zero pad cols wp=0 and wp=129
        int k = t & 15, side = t >> 4;
        u32x4 z = {0u, 0u, 0u, 0u};
        ((u32x4*)(sbrow + (side ? (size_t)(WP - 1) * NC : (size_t)0)))[k] = z;
    }
#pragma unroll
    for (int pp = 0; pp < 8; ++pp) {      // transposed writeback, c-contiguous
        int wloc = pp * 16 + (t >> 4);
        int k = t & 15;
        unsigned int a0 = T[wloc][4 * k + 0];
        unsigned int a1 = T[wloc][4 * k + 1];
        unsigned int a2 = T[wloc][4 * k + 2];
        unsigned int a3 = T[wloc][4 * k + 3];
        u32x4 v = {a0, a1, a2, a3};
        ((u32x4*)(sbrow + (size_t)(wloc + 1) * NC))[k] = v;
    }
}

// ---------------- k2: implicit-GEMM binary conv via MFMA, out += sf[o]*acc ----------------
__global__ __launch_bounds__(256) void k2_conv(
    const unsigned short* __restrict__ SB, const unsigned short* __restrict__ wf,
    const float* __restrict__ sf, float* __restrict__ out) {
    __shared__ float T[4][64][65];        // per-wave [o][w-local] transpose tile
    int bx = blockIdx.x;                  // 1024
    int nb = bx >> 6;
    int h2b = bx & 63;
    int t = threadIdx.x;
    int wid = t >> 6;
    int l = t & 63;
    int lr = l & 15, lg = l >> 4;
    int h = h2b * 2 + (wid >> 1);         // output row for this wave
    int w0 = (wid & 1) * 64;              // output col base
    const unsigned short* sbb = SB + (size_t)nb * HP * WP * NC;
    f32x4 acc[4][4];
    f32x4 zero = {0.f, 0.f, 0.f, 0.f};
#pragma unroll
    for (int mi = 0; mi < 4; ++mi)
#pragma unroll
        for (int ni = 0; ni < 4; ++ni) acc[mi][ni] = zero;
#pragma unroll
    for (int p = 0; p < 9; ++p) {
        int kh = p / 3, kw = p % 3;       // constants after unroll
        const unsigned short* arow =
            sbb + ((size_t)(h + kh) * WP + (w0 + kw + lr)) * NC + lg * 8;
        const unsigned short* brow = wf + p * 8192 + l * 8;
#pragma unroll
        for (int kb = 0; kb < 4; ++kb) {
            bf16x8 af[4], bfr[4];
#pragma unroll
            for (int mi = 0; mi < 4; ++mi)
                af[mi] = *(const bf16x8*)(arow + kb * 32 + mi * 16 * NC);
#pragma unroll
            for (int ni = 0; ni < 4; ++ni)
                bfr[ni] = *(const bf16x8*)(brow + kb * 2048 + ni * 512);
#pragma unroll
            for (int mi = 0; mi < 4; ++mi)
#pragma unroll
                for (int ni = 0; ni < 4; ++ni)
                    acc[mi][ni] = __builtin_amdgcn_mfma_f32_16x16x32_bf16(
                        af[mi], bfr[ni], acc[mi][ni], 0, 0, 0);
        }
    }
    // epilogue: acc -> LDS transpose -> coalesced RMW into pixel-unshuffled out
#pragma unroll
    for (int mi = 0; mi < 4; ++mi)
#pragma unroll
        for (int ni = 0; ni < 4; ++ni)
#pragma unroll
            for (int r = 0; r < 4; ++r)
                T[wid][ni * 16 + lr][mi * 16 + lg * 4 + r] = acc[mi][ni][r];
    __syncthreads();
    int s1 = h & 1, h2 = h >> 1;
    float* ob = out + (((size_t)nb * 256 + s1 * 2) * 64 + h2) * 64;
    int w = w0 + l;
    int lanoff = (w & 1) * 4096 + (w >> 1);
    for (int o = 0; o < 64; ++o) {
        float v = T[wid][o][l] * sf[o];
        ob[(size_t)o * 16384 + lanoff] += v;
    }
}

extern "C" void kernel_launch(void* const* d_in, const int* in_sizes, int n_in,
                              void* d_out, int out_size, void* d_ws, size_t ws_size,
                              hipStream_t stream) {
    const float* x  = (const float*)d_in[0];
    const float* b1 = (const float*)d_in[1];
    const float* pa = (const float*)d_in[2];
    const float* b2 = (const float*)d_in[3];
    const float* cw = (const float*)d_in[4];
    const float* pw = (const float*)d_in[5];
    float* out = (float*)d_out;
    // ws layout: [0,256) sf | [256, 256+147456) wfrag | then SB (padded NHWC bf16, ~69 MB)
    float* sf = (float*)d_ws;
    unsigned short* wfr = (unsigned short*)((char*)d_ws + 256);
    unsigned short* SB  = (unsigned short*)((char*)d_ws + 256 + 147456);

    k_sf<<<64, 64, 0, stream>>>(cw, sf);
    k_wfrag<<<288, 256, 0, stream>>>(cw, wfr);
    k1_signs_shortcut<<<NB * HP, 256, 0, stream>>>(x, b1, pa, b2, pw, SB, out);
    k2_conv<<<1024, 256, 0, stream>>>(SB, wfr, sf, out);
}

// Round 2
// 159.153 us; speedup vs baseline: 1.1275x; 1.1275x over previous
//
#include <hip/hip_runtime.h>
#include <hip/hip_bf16.h>
#include <stdint.h>

typedef __attribute__((ext_vector_type(4))) float f32x4;
typedef __attribute__((ext_vector_type(4))) unsigned int u32x4;
typedef long long i64_t;

#define NB 16
#define NC 128
#define NH 128
#define NW 128
#define NCO 64
#define HP 130
#define WP 130

// ---------------- prep: per-out-channel scale factor sf[o] = mean|w| ----------------
__global__ void k_sf(const float* __restrict__ cw, float* __restrict__ sf) {
    int o = blockIdx.x;          // 64 blocks
    int t = threadIdx.x;         // 64 threads
    const float* p = cw + o * 1152;
    float s = 0.f;
    for (int i = t; i < 1152; i += 64) s += fabsf(p[i]);
#pragma unroll
    for (int off = 32; off > 0; off >>= 1) s += __shfl_down(s, off);
    if (t == 0) sf[o] = s * (1.0f / 1152.0f);
}

// ---------------- prep: weight sign bytes (fp8 e4m3) in MFMA B-fragment order ----------------
// flat byte f = ((p*4+kb)*4+ni)*512 + l*8 + j
// o = ni*16 + (l&15), c = kb*32 + (l>>4)*8 + j, p = kh*3+kw
__global__ void k_wfrag(const float* __restrict__ cw, unsigned char* __restrict__ wf) {
    int f = blockIdx.x * 256 + threadIdx.x;   // < 73728
    int j  = f & 7;
    int l  = (f >> 3) & 63;
    int ni = (f >> 9) & 3;
    int kb = (f >> 11) & 3;
    int p  = f >> 13;
    int o = ni * 16 + (l & 15);
    int c = kb * 32 + (l >> 4) * 8 + j;
    float wv = cw[o * 1152 + c * 9 + p];
    wf[f] = wv > 0.f ? (unsigned char)0x38
                     : (wv < 0.f ? (unsigned char)0xB8 : (unsigned char)0x00);
}

__device__ __forceinline__ unsigned int sgn8(float v, float b1v, float av, float b2v) {
    float t = v + b1v;
    t = fmaxf(t, 0.f) + av * fminf(t, 0.f);
    t += b2v;
    return t > 0.f ? 0x38u : (t < 0.f ? 0xB8u : 0u);
}

// ---------------- k1: activation signs -> SB (padded NHWC fp8), shortcut -> out ----------------
// SB[b][hp][wp][c] bytes, hp = h+1, wp = w+1; pad rows/cols zeroed (conv zero-padding).
__global__ __launch_bounds__(256) void k1_signs_shortcut(
    const float* __restrict__ x, const float* __restrict__ b1,
    const float* __restrict__ pa, const float* __restrict__ b2,
    const float* __restrict__ pw, unsigned char* __restrict__ SB,
    float* __restrict__ out) {
    __shared__ unsigned short T[128][65];   // [w][o] ; packs fp8 of c=2o (lo byte), 2o+1 (hi)
    int bx = blockIdx.x;                    // 16*130
    int nb = bx / 130;
    int hp = bx % 130;
    unsigned char* sbrow = SB + ((size_t)nb * HP + hp) * WP * NC;
    int t = threadIdx.x;
    if (hp == 0 || hp == HP - 1) {          // zero pad rows (16640 B)
        u32x4 z = {0u, 0u, 0u, 0u};
        for (int i = t; i < WP * NC / 16; i += 256)
            ((u32x4*)sbrow)[i] = z;
        return;
    }
    int h = hp - 1;
    int wp2 = t & 63;                       // w pair index: w = 2*wp2, 2*wp2+1
    int oq = t >> 6;                        // 0..3
    const float* xb = x + ((size_t)nb * NC) * NH * NW + (size_t)h * NW + 2 * wp2;
    int s1 = h & 1, h2 = h >> 1;
    float* ob = out + (((size_t)nb * 256 + s1 * 2) * 64 + h2) * 64 + wp2;
#pragma unroll 4
    for (int i = 0; i < 16; ++i) {
        int o = oq * 16 + i;
        int c0 = 2 * o, c1 = c0 + 1;
        float2 x0 = *(const float2*)(xb + (size_t)c0 * NH * NW);
        float2 x1 = *(const float2*)(xb + (size_t)c1 * NH * NW);
        float b10 = b1[c0], b11 = b1[c1];
        float pa0 = pa[c0], pa1 = pa[c1];
        float b20 = b2[c0], b21 = b2[c1];
        unsigned int lo0 = sgn8(x0.x, b10, pa0, b20);
        unsigned int hi0 = sgn8(x1.x, b11, pa1, b21);
        unsigned int lo1 = sgn8(x0.y, b10, pa0, b20);
        unsigned int hi1 = sgn8(x1.y, b11, pa1, b21);
        T[2 * wp2][o]     = (unsigned short)(lo0 | (hi0 << 8));
        T[2 * wp2 + 1][o] = (unsigned short)(lo1 | (hi1 << 8));
        float w0v = pw[c0], w1v = pw[c1];
        ob[(size_t)o * 16384]        = w0v * x0.x + w1v * x1.x;   // s2=0
        ob[(size_t)o * 16384 + 4096] = w0v * x0.y + w1v * x1.y;   // s2=1
    }
    __syncthreads();
    if (t < 32) {                           // zero pad cols wp=0 and wp=129 (128 B each)
        int k = t & 15, side = t >> 4;
        uint2 z = {0u, 0u};
        *(uint2*)(sbrow + (side ? (size_t)(WP - 1) * NC : (size_t)0) + k * 8) = z;
    }
#pragma unroll
    for (int pp = 0; pp < 8; ++pp) {        // transposed writeback, c-contiguous
        int wloc = pp * 16 + (t >> 4);
        int k = t & 15;
        unsigned int t0 = T[wloc][4 * k + 0];
        unsigned int t1 = T[wloc][4 * k + 1];
        unsigned int t2 = T[wloc][4 * k + 2];
        unsigned int t3 = T[wloc][4 * k + 3];
        uint2 v;
        v.x = t0 | (t1 << 16);              // channels 8k..8k+3
        v.y = t2 | (t3 << 16);              // channels 8k+4..8k+7
        *(uint2*)(sbrow + (size_t)(wloc + 1) * NC + k * 8) = v;
    }
}

// ---------------- k2: implicit-GEMM binary conv via fp8 MFMA, out += sf[o]*acc ----------------
__global__ __launch_bounds__(256, 4) void k2_conv(
    const unsigned char* __restrict__ SB, const unsigned char* __restrict__ wf,
    const float* __restrict__ sf, float* __restrict__ out) {
    __shared__ float T3[4][64][33];         // per-wave transpose tile, 33.8 KB total
    int bx = blockIdx.x;                    // 1024
    int nb = bx >> 6;
    int h2b = bx & 63;
    int t = threadIdx.x;
    int wid = t >> 6;
    int l = t & 63;
    int lr = l & 15, lg = l >> 4;
    int h = h2b * 2 + (wid >> 1);           // output row for this wave
    int w0 = (wid & 1) * 64;                // output col base
    const unsigned char* sbb = SB + (size_t)nb * HP * WP * NC;
    f32x4 acc[4][4];
    f32x4 zero = {0.f, 0.f, 0.f, 0.f};
#pragma unroll
    for (int mi = 0; mi < 4; ++mi)
#pragma unroll
        for (int ni = 0; ni < 4; ++ni) acc[mi][ni] = zero;
#pragma unroll
    for (int p = 0; p < 9; ++p) {
        int kh = p / 3, kw = p % 3;         // constants after unroll
        const unsigned char* arow =
            sbb + ((size_t)(h + kh) * WP + (w0 + kw + lr)) * NC + lg * 8;
        const unsigned char* brow = wf + p * 8192 + l * 8;
#pragma unroll
        for (int kb = 0; kb < 4; ++kb) {
            i64_t af[4], bfr[4];
#pragma unroll
            for (int mi = 0; mi < 4; ++mi)
                af[mi] = *(const i64_t*)(arow + kb * 32 + mi * 16 * NC);
#pragma unroll
            for (int ni = 0; ni < 4; ++ni)
                bfr[ni] = *(const i64_t*)(brow + kb * 2048 + ni * 512);
#pragma unroll
            for (int mi = 0; mi < 4; ++mi)
#pragma unroll
                for (int ni = 0; ni < 4; ++ni)
                    acc[mi][ni] = __builtin_amdgcn_mfma_f32_16x16x32_fp8_fp8(
                        af[mi], bfr[ni], acc[mi][ni], 0, 0, 0);
        }
    }
    // epilogue: per-wave LDS transpose in two mi-halves -> coalesced RMW into out
    float (*Tt)[33] = T3[wid];
    int s1 = h & 1, h2 = h >> 1;
    float* ob = out + (((size_t)nb * 256 + s1 * 2) * 64 + h2) * 64;
    int og = l >> 5;
    int wl_lo = l & 31;
#pragma unroll
    for (int half = 0; half < 2; ++half) {
#pragma unroll
        for (int mi2 = 0; mi2 < 2; ++mi2) {
            int mi = half * 2 + mi2;
#pragma unroll
            for (int ni = 0; ni < 4; ++ni)
#pragma unroll
                for (int r = 0; r < 4; ++r)
                    Tt[ni * 16 + lr][mi2 * 16 + lg * 4 + r] = acc[mi][ni][r];
        }
        asm volatile("" ::: "memory");      // keep DS order (per-wave DS is in-order in HW)
        int w = w0 + half * 32 + wl_lo;
        int lanoff = (w & 1) * 4096 + (w >> 1);
        for (int oo = 0; oo < 32; ++oo) {
            int o = 2 * oo + og;
            ob[(size_t)o * 16384 + lanoff] += Tt[o][wl_lo] * sf[o];
        }
        asm volatile("" ::: "memory");      // WAR: half 1 writes after half 0 reads
    }
}

extern "C" void kernel_launch(void* const* d_in, const int* in_sizes, int n_in,
                              void* d_out, int out_size, void* d_ws, size_t ws_size,
                              hipStream_t stream) {
    const float* x  = (const float*)d_in[0];
    const float* b1 = (const float*)d_in[1];
    const float* pa = (const float*)d_in[2];
    const float* b2 = (const float*)d_in[3];
    const float* cw = (const float*)d_in[4];
    const float* pw = (const float*)d_in[5];
    float* out = (float*)d_out;
    // ws layout: [0,256) sf | [256, 256+73728) wfrag fp8 | then SB (padded NHWC fp8, ~34.6 MB)
    float* sf = (float*)d_ws;
    unsigned char* wfr = (unsigned char*)d_ws + 256;
    unsigned char* SB  = (unsigned char*)d_ws + 256 + 73728;

    k_sf<<<64, 64, 0, stream>>>(cw, sf);
    k_wfrag<<<288, 256, 0, stream>>>(cw, wfr);
    k1_signs_shortcut<<<NB * HP, 256, 0, stream>>>(x, b1, pa, b2, pw, SB, out);
    k2_conv<<<1024, 256, 0, stream>>>(SB, wfr, sf, out);
}

// Round 3
// 100.770 us; speedup vs baseline: 1.7808x; 1.5794x over previous
//
#include <hip/hip_runtime.h>
#include <hip/hip_bf16.h>
#include <stdint.h>

typedef __attribute__((ext_vector_type(4))) float f32x4;
typedef __attribute__((ext_vector_type(4))) unsigned int u32x4;
typedef __attribute__((ext_vector_type(2))) long long i64x2;
typedef long long i64_t;

#define NB 16
#define NC 128
#define NH 128
#define NW 128
#define HP 130
#define WP 130

typedef const __attribute__((address_space(1))) void gv_t;
typedef __attribute__((address_space(3))) void lv_t;
__device__ __forceinline__ void gload16(const void* g, void* l) {
    __builtin_amdgcn_global_load_lds((gv_t*)g, (lv_t*)l, 16, 0, 0);
}

// ---------------- prep: per-out-channel scale factor sf[o] = mean|w| ----------------
__global__ void k_sf(const float* __restrict__ cw, float* __restrict__ sf) {
    int o = blockIdx.x;          // 64 blocks
    int t = threadIdx.x;         // 64 threads
    const float* p = cw + o * 1152;
    float s = 0.f;
    for (int i = t; i < 1152; i += 64) s += fabsf(p[i]);
#pragma unroll
    for (int off = 32; off > 0; off >>= 1) s += __shfl_down(s, off);
    if (t == 0) sf[o] = s * (1.0f / 1152.0f);
}

// ---------------- prep: weight sign bytes (fp8 e4m3), B-fragments pairwise-interleaved ----------------
// flat byte f = p*8192 + kb*2048 + nip*1024 + l*16 + nl*8 + j   (ni = nip*2+nl)
// o = ni*16 + (l&15), c = kb*32 + (l>>4)*8 + j
__global__ void k_wfrag(const float* __restrict__ cw, unsigned char* __restrict__ wf) {
    int f = blockIdx.x * 256 + threadIdx.x;   // < 73728
    int j   = f & 7;
    int nl  = (f >> 3) & 1;
    int l   = (f >> 4) & 63;
    int nip = (f >> 10) & 1;
    int kb  = (f >> 11) & 3;
    int p   = f >> 13;
    int o = (nip * 2 + nl) * 16 + (l & 15);
    int c = kb * 32 + (l >> 4) * 8 + j;
    float wv = cw[o * 1152 + c * 9 + p];
    wf[f] = wv > 0.f ? (unsigned char)0x38
                     : (wv < 0.f ? (unsigned char)0xB8 : (unsigned char)0x00);
}

__device__ __forceinline__ unsigned int sgn8(float v, float b1v, float av, float b2v) {
    float t = v + b1v;
    t = fmaxf(t, 0.f) + av * fminf(t, 0.f);
    t += b2v;
    return t > 0.f ? 0x38u : (t < 0.f ? 0xB8u : 0u);
}

// ---------------- k1: activation signs -> SB (padded NHWC fp8, pi-permuted + XOR-swizzled),
//                  shortcut -> out ----------------
// SB[b][hp][wp][ phi(c,wp) ], phi = (lg(c)*32 + kb(c)*8 + j(c)) ^ ((wp&7)<<4)
__global__ __launch_bounds__(256) void k1_signs_shortcut(
    const float* __restrict__ x, const float* __restrict__ b1,
    const float* __restrict__ pa, const float* __restrict__ b2,
    const float* __restrict__ pw, unsigned char* __restrict__ SB,
    float* __restrict__ out) {
    __shared__ unsigned short T[128][65];   // [w][o] ; packs fp8 of c=2o (lo byte), 2o+1 (hi)
    int bx = blockIdx.x;                    // 16*130
    int nb = bx / 130;
    int hp = bx % 130;
    unsigned char* sbrow = SB + ((size_t)nb * HP + hp) * WP * NC;
    int t = threadIdx.x;
    if (hp == 0 || hp == HP - 1) {          // zero pad rows (16640 B)
        u32x4 z = {0u, 0u, 0u, 0u};
        for (int i = t; i < WP * NC / 16; i += 256)
            ((u32x4*)sbrow)[i] = z;
        return;
    }
    int h = hp - 1;
    int wp2 = t & 63;                       // w pair index: w = 2*wp2, 2*wp2+1
    int oq = t >> 6;                        // 0..3
    const float* xb = x + ((size_t)nb * NC) * NH * NW + (size_t)h * NW + 2 * wp2;
    int s1 = h & 1, h2 = h >> 1;
    float* ob = out + (((size_t)nb * 256 + s1 * 2) * 64 + h2) * 64 + wp2;
#pragma unroll 4
    for (int i = 0; i < 16; ++i) {
        int o = oq * 16 + i;
        int c0 = 2 * o, c1 = c0 + 1;
        float2 x0 = *(const float2*)(xb + (size_t)c0 * NH * NW);
        float2 x1 = *(const float2*)(xb + (size_t)c1 * NH * NW);
        float b10 = b1[c0], b11 = b1[c1];
        float pa0 = pa[c0], pa1 = pa[c1];
        float b20 = b2[c0], b21 = b2[c1];
        unsigned int lo0 = sgn8(x0.x, b10, pa0, b20);
        unsigned int hi0 = sgn8(x1.x, b11, pa1, b21);
        unsigned int lo1 = sgn8(x0.y, b10, pa0, b20);
        unsigned int hi1 = sgn8(x1.y, b11, pa1, b21);
        T[2 * wp2][o]     = (unsigned short)(lo0 | (hi0 << 8));
        T[2 * wp2 + 1][o] = (unsigned short)(lo1 | (hi1 << 8));
        float w0v = pw[c0], w1v = pw[c1];
        ob[(size_t)o * 16384]        = w0v * x0.x + w1v * x1.x;   // s2=0
        ob[(size_t)o * 16384 + 4096] = w0v * x0.y + w1v * x1.y;   // s2=1
    }
    __syncthreads();
    if (t < 32) {                           // zero pad cols wp=0 and wp=129 (full 128 B, zeros)
        int k = t & 15, side = t >> 4;
        uint2 z = {0u, 0u};
        *(uint2*)(sbrow + (side ? (size_t)(WP - 1) * NC : (size_t)0) + k * 8) = z;
    }
#pragma unroll
    for (int pp = 0; pp < 8; ++pp) {        // transposed writeback, swizzled positions
        int wloc = pp * 16 + (t >> 4);
        int k = t & 15;                     // channels 8k..8k+7: kb=k>>2, lg=k&3
        unsigned int t0 = T[wloc][4 * k + 0];
        unsigned int t1 = T[wloc][4 * k + 1];
        unsigned int t2 = T[wloc][4 * k + 2];
        unsigned int t3 = T[wloc][4 * k + 3];
        uint2 v;
        v.x = t0 | (t1 << 16);              // bytes: ch 8k..8k+3
        v.y = t2 | (t3 << 16);              // bytes: ch 8k+4..8k+7
        int wp = wloc + 1;
        int logical = (k & 3) * 32 + (k >> 2) * 8;
        int phys = logical ^ ((wp & 7) << 4);
        *(uint2*)(sbrow + (size_t)wp * NC + phys) = v;
    }
}

// ---------------- k2: implicit-GEMM binary conv; A-tile in LDS (one DMA), fp8 MFMA ----------------
__global__ __launch_bounds__(256, 2) void k2_conv(
    const unsigned char* __restrict__ SB, const unsigned char* __restrict__ wf,
    const float* __restrict__ sf, float* __restrict__ out) {
    __shared__ __align__(16) unsigned char AT[66560];   // 4 padded rows x 130 x 128B
    int bxr = blockIdx.x;
    int bx = (bxr & 7) * 128 + (bxr >> 3);  // XCD swizzle (1024 % 8 == 0, bijective)
    int nb = bx >> 6;
    int h2b = bx & 63;
    int t = threadIdx.x;
    int wid = t >> 6;
    int l = t & 63;
    int lr = l & 15, lg = l >> 4;
    // stage 66,560 B = 4160 x 16 B, linear (SB rows hp = 2*h2b .. 2*h2b+3 are contiguous)
    const unsigned char* gsrc = SB + ((size_t)nb * HP + 2 * h2b) * (WP * NC);
#pragma unroll
    for (int i = 0; i < 16; ++i)
        gload16(gsrc + ((size_t)(i * 256 + t)) * 16, AT + (i * 256 + wid * 64) * 16);
    if (wid == 0)
        gload16(gsrc + ((size_t)(4096 + l)) * 16, AT + 4096 * 16);

    int h = h2b * 2 + (wid >> 1);           // output row for this wave
    int w0 = (wid & 1) * 64;                // output col base
    f32x4 acc[4][4];
    f32x4 zero = {0.f, 0.f, 0.f, 0.f};
#pragma unroll
    for (int mi = 0; mi < 4; ++mi)
#pragma unroll
        for (int ni = 0; ni < 4; ++ni) acc[mi][ni] = zero;
    __syncthreads();

#pragma unroll
    for (int p = 0; p < 9; ++p) {
        int kh = p / 3, kw = p % 3;         // constants after unroll
        int rho = (wid >> 1) + kh;          // local padded row 0..3
        int wp = w0 + kw + lr;
        int sb7 = wp & 7;
        const unsigned char* ap = AT + (size_t)(rho * WP + wp) * NC;
        const unsigned char* brow = wf + p * 8192 + l * 16;
        i64_t bfr[4][4];
#pragma unroll
        for (int kb = 0; kb < 4; ++kb) {    // B: 16B/lane coalesced, L2-hot
            i64x2 b01 = *(const i64x2*)(brow + kb * 2048);
            i64x2 b23 = *(const i64x2*)(brow + kb * 2048 + 1024);
            bfr[kb][0] = b01.x; bfr[kb][1] = b01.y;
            bfr[kb][2] = b23.x; bfr[kb][3] = b23.y;
        }
        int off0 = ((lg * 2) ^ sb7) << 4;   // logical 16B-block -> physical (XOR swizzle)
        int off1 = ((lg * 2 + 1) ^ sb7) << 4;
#pragma unroll
        for (int mi = 0; mi < 4; ++mi) {    // 2 x ds_read_b128 = all 4 kb fragments
            i64x2 a01 = *(const i64x2*)(ap + mi * 2048 + off0);
            i64x2 a23 = *(const i64x2*)(ap + mi * 2048 + off1);
            i64_t af[4] = {a01.x, a01.y, a23.x, a23.y};
#pragma unroll
            for (int kb = 0; kb < 4; ++kb)
#pragma unroll
                for (int ni = 0; ni < 4; ++ni)
                    acc[mi][ni] = __builtin_amdgcn_mfma_f32_16x16x32_fp8_fp8(
                        af[kb], bfr[kb][ni], acc[mi][ni], 0, 0, 0);
        }
    }
    __syncthreads();                        // A-tile dead; reuse LDS for epilogue transpose
    float (*Tt)[33] = (float (*)[33])(AT + wid * 8448);
    int s1 = h & 1, h2 = h >> 1;
    float* ob = out + (((size_t)nb * 256 + s1 * 2) * 64 + h2) * 64;
    int og = l >> 5;
    int wl_lo = l & 31;
#pragma unroll
    for (int half = 0; half < 2; ++half) {
#pragma unroll
        for (int mi2 = 0; mi2 < 2; ++mi2) {
            int mi = half * 2 + mi2;
#pragma unroll
            for (int ni = 0; ni < 4; ++ni)
#pragma unroll
                for (int r = 0; r < 4; ++r)
                    Tt[ni * 16 + lr][mi2 * 16 + lg * 4 + r] = acc[mi][ni][r];
        }
        asm volatile("" ::: "memory");      // per-wave DS in-order; pin compiler order
        int w = w0 + half * 32 + wl_lo;
        int lanoff = (w & 1) * 4096 + (w >> 1);
        for (int oo = 0; oo < 32; ++oo) {
            int o = 2 * oo + og;
            ob[(size_t)o * 16384 + lanoff] += Tt[o][wl_lo] * sf[o];
        }
        asm volatile("" ::: "memory");      // WAR: half 1 writes after half 0 reads
    }
}

extern "C" void kernel_launch(void* const* d_in, const int* in_sizes, int n_in,
                              void* d_out, int out_size, void* d_ws, size_t ws_size,
                              hipStream_t stream) {
    const float* x  = (const float*)d_in[0];
    const float* b1 = (const float*)d_in[1];
    const float* pa = (const float*)d_in[2];
    const float* b2 = (const float*)d_in[3];
    const float* cw = (const float*)d_in[4];
    const float* pw = (const float*)d_in[5];
    float* out = (float*)d_out;
    // ws layout: [0,256) sf | [256, 256+73728) wfrag fp8 | then SB (padded NHWC fp8, ~34.6 MB)
    float* sf = (float*)d_ws;
    unsigned char* wfr = (unsigned char*)d_ws + 256;
    unsigned char* SB  = (unsigned char*)d_ws + 256 + 73728;

    k_sf<<<64, 64, 0, stream>>>(cw, sf);
    k_wfrag<<<288, 256, 0, stream>>>(cw, wfr);
    k1_signs_shortcut<<<NB * HP, 256, 0, stream>>>(x, b1, pa, b2, pw, SB, out);
    k2_conv<<<1024, 256, 0, stream>>>(SB, wfr, sf, out);
}

// Round 4
// 96.703 us; speedup vs baseline: 1.8556x; 1.0420x over previous
//
#include <hip/hip_runtime.h>
#include <hip/hip_bf16.h>
#include <stdint.h>

typedef __attribute__((ext_vector_type(4))) float f32x4;
typedef __attribute__((ext_vector_type(4))) unsigned int u32x4;
typedef __attribute__((ext_vector_type(2))) long long i64x2;
typedef long long i64_t;

#define NB 16
#define NC 128
#define NH 128
#define NW 128
#define HP 130
#define WP 130

typedef const __attribute__((address_space(1))) void gv_t;
typedef __attribute__((address_space(3))) void lv_t;
__device__ __forceinline__ void gload16(const void* g, void* l) {
    __builtin_amdgcn_global_load_lds((gv_t*)g, (lv_t*)l, 16, 0, 0);
}

// ---------------- prep (merged): wfrag for all blocks; sf in blocks < 64 ----------------
// wfrag flat byte f = p*8192 + kb*2048 + nip*1024 + l*16 + nl*8 + j   (ni = nip*2+nl)
// o = ni*16 + (l&15), c = kb*32 + (l>>4)*8 + j
__global__ __launch_bounds__(256) void k_prep(const float* __restrict__ cw,
                                              float* __restrict__ sf,
                                              unsigned char* __restrict__ wf) {
    int b = blockIdx.x, t = threadIdx.x;    // 288 blocks
    int f = b * 256 + t;                    // < 73728
    int j   = f & 7;
    int nl  = (f >> 3) & 1;
    int l   = (f >> 4) & 63;
    int nip = (f >> 10) & 1;
    int kb  = (f >> 11) & 3;
    int p   = f >> 13;
    int o = (nip * 2 + nl) * 16 + (l & 15);
    int c = kb * 32 + (l >> 4) * 8 + j;
    float wv = cw[o * 1152 + c * 9 + p];
    wf[f] = wv > 0.f ? (unsigned char)0x38
                     : (wv < 0.f ? (unsigned char)0xB8 : (unsigned char)0x00);
    if (b < 64) {                           // sf[b] = mean|w| over 1152
        __shared__ float red[4];
        const float* pp = cw + b * 1152;
        float s = 0.f;
        for (int i = t; i < 1152; i += 256) s += fabsf(pp[i]);
#pragma unroll
        for (int off = 32; off > 0; off >>= 1) s += __shfl_down(s, off);
        if ((t & 63) == 0) red[t >> 6] = s;
        __syncthreads();
        if (t == 0) sf[b] = (red[0] + red[1] + red[2] + red[3]) * (1.0f / 1152.0f);
    }
}

__device__ __forceinline__ unsigned int sgn8(float v, float b1v, float av, float b2v) {
    float t = v + b1v;
    t = fmaxf(t, 0.f) + av * fminf(t, 0.f);
    t += b2v;
    return t > 0.f ? 0x38u : (t < 0.f ? 0xB8u : 0u);
}

// ---------------- k1: activation signs -> SB (padded NHWC fp8, pi+XOR layout, ADJACENT stores),
//                  shortcut -> out ----------------
// Layout identical to round 3: channel c of column wp lives at byte
// ((lg(c)*4+kb(c))*8 + j(c)) with the 16B-block index XOR'd by (wp&7).
// Lane k writes position k*8 (contiguous 128B per 16 lanes) and gathers the
// content that belongs there: ell = (((k>>1)^(wp&7))<<1)|(k&1).
__global__ __launch_bounds__(256) void k1_signs_shortcut(
    const float* __restrict__ x, const float* __restrict__ b1,
    const float* __restrict__ pa, const float* __restrict__ b2,
    const float* __restrict__ pw, unsigned char* __restrict__ SB,
    float* __restrict__ out) {
    __shared__ unsigned short T[128][65];   // [w][o] ; packs fp8 of c=2o (lo byte), 2o+1 (hi)
    int bx = blockIdx.x;                    // 16*130
    int nb = bx / 130;
    int hp = bx % 130;
    unsigned char* sbrow = SB + ((size_t)nb * HP + hp) * WP * NC;
    int t = threadIdx.x;
    if (hp == 0 || hp == HP - 1) {          // zero pad rows (16640 B)
        u32x4 z = {0u, 0u, 0u, 0u};
        for (int i = t; i < WP * NC / 16; i += 256)
            ((u32x4*)sbrow)[i] = z;
        return;
    }
    int h = hp - 1;
    int wp2 = t & 63;                       // w pair index: w = 2*wp2, 2*wp2+1
    int oq = t >> 6;                        // 0..3
    const float* xb = x + ((size_t)nb * NC) * NH * NW + (size_t)h * NW + 2 * wp2;
    int s1 = h & 1, h2 = h >> 1;
    float* ob = out + (((size_t)nb * 256 + s1 * 2) * 64 + h2) * 64 + wp2;
#pragma unroll 4
    for (int i = 0; i < 16; ++i) {
        int o = oq * 16 + i;
        int c0 = 2 * o, c1 = c0 + 1;
        float2 x0 = *(const float2*)(xb + (size_t)c0 * NH * NW);
        float2 x1 = *(const float2*)(xb + (size_t)c1 * NH * NW);
        float b10 = b1[c0], b11 = b1[c1];
        float pa0 = pa[c0], pa1 = pa[c1];
        float b20 = b2[c0], b21 = b2[c1];
        unsigned int lo0 = sgn8(x0.x, b10, pa0, b20);
        unsigned int hi0 = sgn8(x1.x, b11, pa1, b21);
        unsigned int lo1 = sgn8(x0.y, b10, pa0, b20);
        unsigned int hi1 = sgn8(x1.y, b11, pa1, b21);
        T[2 * wp2][o]     = (unsigned short)(lo0 | (hi0 << 8));
        T[2 * wp2 + 1][o] = (unsigned short)(lo1 | (hi1 << 8));
        float w0v = pw[c0], w1v = pw[c1];
        ob[(size_t)o * 16384]        = w0v * x0.x + w1v * x1.x;   // s2=0
        ob[(size_t)o * 16384 + 4096] = w0v * x0.y + w1v * x1.y;   // s2=1
    }
    __syncthreads();
    if (t < 32) {                           // zero pad cols wp=0 and wp=129 (zeros: swizzle-invariant)
        int k = t & 15, side = t >> 4;
        uint2 z = {0u, 0u};
        *(uint2*)(sbrow + (side ? (size_t)(WP - 1) * NC : (size_t)0) + k * 8) = z;
    }
#pragma unroll
    for (int pp = 0; pp < 8; ++pp) {        // adjacent writeback, permuted gather
        int wloc = pp * 16 + (t >> 4);
        int k = t & 15;                     // physical 8B-unit index
        int wp = wloc + 1;
        int ell = (((k >> 1) ^ (wp & 7)) << 1) | (k & 1);   // logical pi-unit at this slot
        int o0 = (ell & 3) * 16 + (ell >> 2) * 4;           // its 4 channel-pairs in T
        unsigned int t0 = T[wloc][o0 + 0];
        unsigned int t1 = T[wloc][o0 + 1];
        unsigned int t2 = T[wloc][o0 + 2];
        unsigned int t3 = T[wloc][o0 + 3];
        uint2 v;
        v.x = t0 | (t1 << 16);
        v.y = t2 | (t3 << 16);
        *(uint2*)(sbrow + (size_t)wp * NC + k * 8) = v;
    }
}

// ---------------- k2: implicit-GEMM binary conv; A-tile in LDS (one DMA), fp8 MFMA ----------------
__global__ __launch_bounds__(256, 2) void k2_conv(
    const unsigned char* __restrict__ SB, const unsigned char* __restrict__ wf,
    const float* __restrict__ sf, float* __restrict__ out) {
    __shared__ __align__(16) unsigned char AT[66560];   // 4 padded rows x 130 x 128B
    int bxr = blockIdx.x;
    int bx = (bxr & 7) * 128 + (bxr >> 3);  // XCD swizzle (1024 % 8 == 0, bijective)
    int nb = bx >> 6;
    int h2b = bx & 63;
    int t = threadIdx.x;
    int wid = t >> 6;
    int l = t & 63;
    int lr = l & 15, lg = l >> 4;
    // stage 66,560 B = 4160 x 16 B, linear (SB rows hp = 2*h2b .. 2*h2b+3 are contiguous)
    const unsigned char* gsrc = SB + ((size_t)nb * HP + 2 * h2b) * (WP * NC);
#pragma unroll
    for (int i = 0; i < 16; ++i)
        gload16(gsrc + ((size_t)(i * 256 + t)) * 16, AT + (i * 256 + wid * 64) * 16);
    if (wid == 0)
        gload16(gsrc + ((size_t)(4096 + l)) * 16, AT + 4096 * 16);

    int h = h2b * 2 + (wid >> 1);           // output row for this wave
    int w0 = (wid & 1) * 64;                // output col base
    f32x4 acc[4][4];
    f32x4 zero = {0.f, 0.f, 0.f, 0.f};
#pragma unroll
    for (int mi = 0; mi < 4; ++mi)
#pragma unroll
        for (int ni = 0; ni < 4; ++ni) acc[mi][ni] = zero;
    __syncthreads();

#pragma unroll
    for (int p = 0; p < 9; ++p) {
        int kh = p / 3, kw = p % 3;         // constants after unroll
        int rho = (wid >> 1) + kh;          // local padded row 0..3
        int wp = w0 + kw + lr;
        int sb7 = wp & 7;
        const unsigned char* ap = AT + (size_t)(rho * WP + wp) * NC;
        const unsigned char* brow = wf + p * 8192 + l * 16;
        i64_t bfr[4][4];
#pragma unroll
        for (int kb = 0; kb < 4; ++kb) {    // B: 16B/lane coalesced, L2-hot
            i64x2 b01 = *(const i64x2*)(brow + kb * 2048);
            i64x2 b23 = *(const i64x2*)(brow + kb * 2048 + 1024);
            bfr[kb][0] = b01.x; bfr[kb][1] = b01.y;
            bfr[kb][2] = b23.x; bfr[kb][3] = b23.y;
        }
        int off0 = ((lg * 2) ^ sb7) << 4;   // logical 16B-block -> physical (XOR swizzle)
        int off1 = ((lg * 2 + 1) ^ sb7) << 4;
#pragma unroll
        for (int mi = 0; mi < 4; ++mi) {    // 2 x ds_read_b128 = all 4 kb fragments
            i64x2 a01 = *(const i64x2*)(ap + mi * 2048 + off0);
            i64x2 a23 = *(const i64x2*)(ap + mi * 2048 + off1);
            i64_t af[4] = {a01.x, a01.y, a23.x, a23.y};
#pragma unroll
            for (int kb = 0; kb < 4; ++kb)
#pragma unroll
                for (int ni = 0; ni < 4; ++ni)
                    acc[mi][ni] = __builtin_amdgcn_mfma_f32_16x16x32_fp8_fp8(
                        af[kb], bfr[kb][ni], acc[mi][ni], 0, 0, 0);
        }
    }
    __syncthreads();                        // A-tile dead; reuse LDS for epilogue transpose
    float (*Tt)[33] = (float (*)[33])(AT + wid * 8448);
    int s1 = h & 1, h2 = h >> 1;
    float* ob = out + (((size_t)nb * 256 + s1 * 2) * 64 + h2) * 64;
    int og = l >> 5;
    int wl_lo = l & 31;
#pragma unroll
    for (int half = 0; half < 2; ++half) {
#pragma unroll
        for (int mi2 = 0; mi2 < 2; ++mi2) {
            int mi = half * 2 + mi2;
#pragma unroll
            for (int ni = 0; ni < 4; ++ni)
#pragma unroll
                for (int r = 0; r < 4; ++r)
                    Tt[ni * 16 + lr][mi2 * 16 + lg * 4 + r] = acc[mi][ni][r];
        }
        asm volatile("" ::: "memory");      // per-wave DS in-order; pin compiler order
        int w = w0 + half * 32 + wl_lo;
        int lanoff = (w & 1) * 4096 + (w >> 1);
        for (int oo = 0; oo < 32; ++oo) {
            int o = 2 * oo + og;
            ob[(size_t)o * 16384 + lanoff] += Tt[o][wl_lo] * sf[o];
        }
        asm volatile("" ::: "memory");      // WAR: half 1 writes after half 0 reads
    }
}

extern "C" void kernel_launch(void* const* d_in, const int* in_sizes, int n_in,
                              void* d_out, int out_size, void* d_ws, size_t ws_size,
                              hipStream_t stream) {
    const float* x  = (const float*)d_in[0];
    const float* b1 = (const float*)d_in[1];
    const float* pa = (const float*)d_in[2];
    const float* b2 = (const float*)d_in[3];
    const float* cw = (const float*)d_in[4];
    const float* pw = (const float*)d_in[5];
    float* out = (float*)d_out;
    // ws layout: [0,256) sf | [256, 256+73728) wfrag fp8 | then SB (padded NHWC fp8, ~34.6 MB)
    float* sf = (float*)d_ws;
    unsigned char* wfr = (unsigned char*)d_ws + 256;
    unsigned char* SB  = (unsigned char*)d_ws + 256 + 73728;

    k_prep<<<288, 256, 0, stream>>>(cw, sf, wfr);
    k1_signs_shortcut<<<NB * HP, 256, 0, stream>>>(x, b1, pa, b2, pw, SB, out);
    k2_conv<<<1024, 256, 0, stream>>>(SB, wfr, sf, out);
}